// Round 15
// baseline (194.451 us; speedup 1.0000x reference)
//
#include <hip/hip_runtime.h>
#include <hip/hip_fp16.h>

// Trilinear grid interpolation — w-split windowed binning + fp16-LDS gather,
// 128-thread gather blocks (anti phase-lock).
//   velocity: [B, 3, G, G, G] f32, points: [B, N, 3] f32, bb: [3,2] f32
//   out: [B, N, 3] f32
//
// R13 ledger: gather ~130us vs ~95us ideal; HBM only ~3.1TB/s during gather
// because 8 lockstep 4-wave blocks/CU alternate stage-burst / compute-burst
// (phase-locked). R14: split bins along w (2048 bins/batch, staged region
// 25 rows x 68 w fp16 = 10.2KB) + 128-thread blocks -> ~14 independent
// blocks/CU with staggered lifecycles; stage of one block overlaps compute
// of another. Stage volume unchanged. Payload stays 8B quantized (R13).

constexpr int G = 128;
constexpr long long G3 = (long long)G * G * G;   // 1<<21
constexpr int NSLAB = 8;            // == #XCDs
constexpr int NBIN = 2048;          // (iu/4)<<6 | (iv/4)<<1 | (iw>=64)
constexpr int WINPTS = 4096;        // points per window block
constexpr int NIT = WINPTS / 256;   // 16
constexpr int MAXWIN = 64;          // gather LDS arrays cap (N <= 64*4096)
constexpr int WROW = 68;            // staged w-cells per row (17 float4)

// ---------------- pass 1: windowed binning (hist + scan + scatter) ----------
__global__ __launch_bounds__(256) void bin_kernel(
    const float* __restrict__ pts,   // [B,N,3]
    const float* __restrict__ bb,    // [3,2]
    int* __restrict__ Pt,            // [B*NBIN][nwin] window-local bin offsets
    unsigned long long* __restrict__ payload,  // [B*nwin][WINPTS]
    int N, int nwin)
{
    __shared__ int hist[NBIN];       // 8 KB
    __shared__ int psum[256];

    int b = blockIdx.x / nwin;
    int w = blockIdx.x % nwin;
    for (int i = threadIdx.x; i < NBIN; i += 256) hist[i] = 0;
    __syncthreads();

    const float Gm1 = (float)(G - 1);
    float bx0 = bb[0], bx1 = bb[1];
    float by0 = bb[2], by1 = bb[3];
    float bz0 = bb[4], bz1 = bb[5];
    long long pbase = (long long)b * N;
    int n0 = w * WINPTS;

    // phase 1: histogram; quantize+cache q in registers (static idx via unroll)
    unsigned long long qc[NIT];
    #pragma unroll
    for (int it = 0; it < NIT; ++it) {
        int n = n0 + it * 256 + threadIdx.x;
        qc[it] = ~0ull;
        if (n < N) {
            const float* p = pts + (pbase + n) * 3;
            float u  = (p[0] - bx0) / (bx1 - bx0) * Gm1;
            float v  = (p[1] - by0) / (by1 - by0) * Gm1;
            float wz = (p[2] - bz0) / (bz1 - bz0) * Gm1;
            u  = fminf(fmaxf(u, 0.f), Gm1);
            v  = fminf(fmaxf(v, 0.f), Gm1);
            wz = fminf(fmaxf(wz, 0.f), Gm1);
            unsigned int qu = (unsigned int)(u * 1024.0f);   // floor-quant
            unsigned int qv = (unsigned int)(v * 1024.0f);
            unsigned int qw = (unsigned int)(wz * 1024.0f);
            int nl = n - n0;                                  // 12 bits
            qc[it] = (unsigned long long)qu
                   | ((unsigned long long)qv << 17)
                   | ((unsigned long long)qw << 34)
                   | ((unsigned long long)nl << 51);
            int bin = ((qu >> 12) << 6) | (((qv >> 12)) << 1) | (qw >> 16);
            atomicAdd(&hist[bin], 1);
        }
    }
    __syncthreads();

    // in-block exclusive scan of 2048 bins: thread t owns bins 8t..8t+7
    int t = threadIdx.x;
    int l[8], s = 0;
    #pragma unroll
    for (int j = 0; j < 8; ++j) { l[j] = hist[8 * t + j]; s += l[j]; }
    psum[t] = s;
    __syncthreads();
    for (int off = 1; off < 256; off <<= 1) {
        int v = (t >= off) ? psum[t - off] : 0;
        __syncthreads();
        psum[t] += v;
        __syncthreads();
    }
    int run = psum[t] - s;   // exclusive prefix of this thread's 8 bins

    // write Pt (bin-major) and convert hist -> cursor
    long long prow = ((long long)b * NBIN + 8 * t) * nwin + w;
    #pragma unroll
    for (int j = 0; j < 8; ++j) {
        Pt[prow + (long long)j * nwin] = run;
        hist[8 * t + j] = run;
        run += l[j];
    }
    __syncthreads();

    // phase 2: rank via LDS cursor, write 8B payload into private segment
    unsigned long long* seg = payload + (long long)(b * nwin + w) * WINPTS;
    #pragma unroll
    for (int it = 0; it < NIT; ++it) {
        unsigned long long q = qc[it];
        if (q != ~0ull) {
            unsigned int qu = (unsigned int)(q & 0x1FFFF);
            unsigned int qv = (unsigned int)((q >> 17) & 0x1FFFF);
            unsigned int qw = (unsigned int)((q >> 34) & 0x1FFFF);
            int bin = ((qu >> 12) << 6) | (((qv >> 12)) << 1) | (qw >> 16);
            int pos = atomicAdd(&hist[bin], 1);
            seg[pos] = q;
        }
    }
}

// ---------------- pass 2: binned gather, fp16 LDS, 128-thread blocks --------
__global__ __launch_bounds__(128) void trilerp_lds_kernel(
    const float* __restrict__ vel,       // [B,3,G,G,G]
    const int* __restrict__ Pt,          // [B*NBIN][nwin]
    const unsigned long long* __restrict__ payload,  // [B*nwin][WINPTS]
    float* __restrict__ out,             // [B,N,3]
    int N, int nwin)
{
    // blockIdx.x = slab + 8*(b*256 + j*64 + iv4*2 + wh); iu4 = slab*4 + j
    __shared__ unsigned short s_h[3 * 25 * WROW];  // 10.2 KB
    __shared__ int loc[MAXWIN];
    __shared__ int sc[MAXWIN];                     // counts -> inclusive prefix

    int x = blockIdx.x;
    int slab = x & (NSLAB - 1);
    int rest = x >> 3;
    int wh   = rest & 1;
    int iv4  = (rest >> 1) & 31;
    int j    = (rest >> 6) & 3;
    int b    = rest >> 8;
    int iu4  = (slab << 2) | j;
    int binLocal = (iu4 << 6) | (iv4 << 1) | wh;
    long long lin = (long long)b * NBIN + binLocal;

    int tid = threadIdx.x;
    if (tid < nwin) {
        int l  = Pt[lin * nwin + tid];
        int nl = (binLocal < NBIN - 1) ? Pt[(lin + 1) * nwin + tid]
                                       : min(WINPTS, N - tid * WINPTS);
        loc[tid] = l;
        sc[tid]  = nl - l;                  // count of this bin in window tid
    } else if (tid < MAXWIN) {
        loc[tid] = 0; sc[tid] = 0;
    }

    // stage 3 ch x 25 rows x 17 float4 (68 w-cells from wb), f32 -> fp16 LDS
    int u0 = iu4 << 2, v0 = iv4 << 2;
    int wb = wh * 60;                       // half0: [0,68); half1: [60,128)
    for (int k = 0; k < 10; ++k) {
        int idx = tid + k * 128;
        if (idx < 1275) {
            int f4 = idx % 17;
            int ru = idx / 17;
            int ch = ru / 25;
            int r  = ru - ch * 25;
            int gu = min(u0 + r / 5, G - 1);
            int gv = min(v0 + (r - (r / 5) * 5), G - 1);
            long long src = (((long long)b * 3 + ch) << 21) + ((long long)gu << 14) + (gv << 7) + wb + (f4 << 2);
            float4 val = *reinterpret_cast<const float4*>(vel + src);
            unsigned int lo32 = (unsigned int)__half_as_ushort(__float2half(val.x))
                              | ((unsigned int)__half_as_ushort(__float2half(val.y)) << 16);
            unsigned int hi32 = (unsigned int)__half_as_ushort(__float2half(val.z))
                              | ((unsigned int)__half_as_ushort(__float2half(val.w)) << 16);
            *reinterpret_cast<uint2*>(&s_h[(ch * 25 + r) * WROW + (f4 << 2)]) = make_uint2(lo32, hi32);
        }
    }
    __syncthreads();

    // inclusive prefix over window counts (all threads hit barriers)
    for (int off = 1; off < MAXWIN; off <<= 1) {
        int v = 0;
        if (tid < MAXWIN && tid >= off) v = sc[tid - off];
        __syncthreads();
        if (tid < MAXWIN) sc[tid] += v;
        __syncthreads();
    }
    int total = sc[nwin - 1];
    const float INV1024 = 1.0f / 1024.0f;

    auto h2f = [](unsigned short us) -> float {
        return __half2float(__ushort_as_half(us));
    };

    for (int i = tid; i < total; i += 128) {
        // smallest w with sc[w] > i
        int lo2 = 0, hi2 = nwin - 1;
        while (lo2 < hi2) { int mid = (lo2 + hi2) >> 1; if (sc[mid] > i) hi2 = mid; else lo2 = mid + 1; }
        int w = lo2;
        int excl = (w == 0) ? 0 : sc[w - 1];
        long long pidx = (long long)(b * nwin + w) * WINPTS + loc[w] + (i - excl);
        unsigned long long q = payload[pidx];
        unsigned int qu = (unsigned int)(q & 0x1FFFF);
        unsigned int qv = (unsigned int)((q >> 17) & 0x1FFFF);
        unsigned int qw = (unsigned int)((q >> 34) & 0x1FFFF);
        int nl = (int)(q >> 51);
        int t = (int)((long long)b * N + w * WINPTS + nl);

        float u  = (float)qu * INV1024;
        float v  = (float)qv * INV1024;
        float wq = (float)qw * INV1024;

        float fu = floorf(u);
        float fv = floorf(v);
        float fw = floorf(wq);

        float du = u - fu, dv = v - fv, dw = wq - fw;  // frac
        float gu = fu + 1.0f - u;                      // gfrac
        float gv = fv + 1.0f - v;
        float gw = fw + 1.0f - wq;

        int iu1 = (int)fu, iv1 = (int)fv, iw1 = (int)fw;
        int iu2 = min(iu1 + 1, G - 1);
        int iv2 = min(iv1 + 1, G - 1);
        int iwb = min(iw1, G - 2);
        bool lo = (iw1 <= G - 2);

        float w11 = gu * gv, w12 = gu * dv, w21 = du * gv, w22 = du * dv;

        int du1 = iu1 - u0, dv1 = iv1 - v0;
        int du2 = iu2 - u0, dv2 = iv2 - v0;
        int wl = iwb - wb;                  // LDS w index

        float o[3];
        #pragma unroll
        for (int ch = 0; ch < 3; ++ch) {
            int rb = ch * 25;
            int b11 = (rb + du1 * 5 + dv1) * WROW + wl;
            int b12 = (rb + du1 * 5 + dv2) * WROW + wl;
            int b21 = (rb + du2 * 5 + dv1) * WROW + wl;
            int b22 = (rb + du2 * 5 + dv2) * WROW + wl;
            float l11 = h2f(s_h[b11]), h11 = h2f(s_h[b11 + 1]);
            float l12 = h2f(s_h[b12]), h12 = h2f(s_h[b12 + 1]);
            float l21 = h2f(s_h[b21]), h21 = h2f(s_h[b21 + 1]);
            float l22 = h2f(s_h[b22]), h22 = h2f(s_h[b22 + 1]);
            float a11 = lo ? l11 : h11;
            float a12 = lo ? l12 : h12;
            float a21 = lo ? l21 : h21;
            float a22 = lo ? l22 : h22;
            o[ch] = w11 * (gw * a11 + dw * h11)
                  + w12 * (gw * a12 + dw * h12)
                  + w21 * (gw * a21 + dw * h21)
                  + w22 * (gw * a22 + dw * h22);
        }

        float* op = out + (long long)t * 3;
        op[0] = o[0]; op[1] = o[1]; op[2] = o[2];
    }
}

// ---- fallback (R3): f32 broadcast scan, no workspace ----
__global__ __launch_bounds__(256) void trilerp_pair_kernel(
    const float* __restrict__ vel, const float* __restrict__ pts,
    const float* __restrict__ bb, float* __restrict__ out,
    int N, int nchunk)
{
    int bid  = blockIdx.x;
    int slab = bid & (NSLAB - 1);
    int t    = bid >> 3;
    int c    = t % nchunk;
    int b    = t / nchunk;
    int n = c * 256 + threadIdx.x;
    if (n >= N) return;

    float bx0 = bb[0], bx1 = bb[1];
    float by0 = bb[2], by1 = bb[3];
    float bz0 = bb[4], bz1 = bb[5];
    long long pi = (long long)b * N + n;
    const float* p = pts + pi * 3;
    float px = p[0], py = p[1], pz = p[2];
    const float Gm1 = (float)(G - 1);
    float u = (px - bx0) / (bx1 - bx0) * Gm1;
    float fu = fminf(fmaxf(floorf(u), 0.f), Gm1);
    int iu1 = (int)fu;
    if ((iu1 >> 4) != slab) return;
    float v = (py - by0) / (by1 - by0) * Gm1;
    float w = (pz - bz0) / (bz1 - bz0) * Gm1;
    float fv = fminf(fmaxf(floorf(v), 0.f), Gm1);
    float fw = fminf(fmaxf(floorf(w), 0.f), Gm1);
    float du = u - fu, dv = v - fv, dw = w - fw;
    float gu = fu + 1.0f - u, gv = fv + 1.0f - v, gw = fw + 1.0f - w;
    int iv1 = (int)fv, iw1 = (int)fw;
    int iu2 = min(iu1 + 1, G - 1);
    int iv2 = min(iv1 + 1, G - 1);
    int iwb = min(iw1, G - 2);
    bool lo = (iw1 <= G - 2);
    float w11 = gu * gv, w12 = gu * dv, w21 = du * gv, w22 = du * dv;
    const float* vb = vel + (long long)b * 3 * G3;
    long long o11 = (long long)((iu1 << 7) + iv1) * G + iwb;
    long long o12 = (long long)((iu1 << 7) + iv2) * G + iwb;
    long long o21 = (long long)((iu2 << 7) + iv1) * G + iwb;
    long long o22 = (long long)((iu2 << 7) + iv2) * G + iwb;
    float o[3];
    #pragma unroll
    for (int chn = 0; chn < 3; ++chn) {
        const float* vc = vb + (long long)chn * G3;
        float2 p11 = *reinterpret_cast<const float2*>(vc + o11);
        float2 p12 = *reinterpret_cast<const float2*>(vc + o12);
        float2 p21 = *reinterpret_cast<const float2*>(vc + o21);
        float2 p22 = *reinterpret_cast<const float2*>(vc + o22);
        float a11 = lo ? p11.x : p11.y;
        float a12 = lo ? p12.x : p12.y;
        float a21 = lo ? p21.x : p21.y;
        float a22 = lo ? p22.x : p22.y;
        o[chn] = w11 * (gw * a11 + dw * p11.y)
               + w12 * (gw * a12 + dw * p12.y)
               + w21 * (gw * a21 + dw * p21.y)
               + w22 * (gw * a22 + dw * p22.y);
    }
    float* op = out + pi * 3;
    op[0] = o[0]; op[1] = o[1]; op[2] = o[2];
}

extern "C" void kernel_launch(void* const* d_in, const int* in_sizes, int n_in,
                              void* d_out, int out_size, void* d_ws, size_t ws_size,
                              hipStream_t stream) {
    const float* vel = (const float*)d_in[0];
    const float* pts = (const float*)d_in[1];
    const float* bb  = (const float*)d_in[2];
    float* out = (float*)d_out;

    int B = (int)(in_sizes[0] / (3 * G3));       // 16
    int N = in_sizes[1] / (3 * B);               // 200000
    int nwin = (N + WINPTS - 1) / WINPTS;        // 49

    auto align256 = [](size_t x) { return (x + 255) & ~(size_t)255; };
    size_t off_pt  = 0;
    size_t sz_pt   = (size_t)B * NBIN * nwin * 4;            // 6.4 MB
    size_t off_pay = align256(off_pt + sz_pt);
    size_t sz_pay  = (size_t)B * nwin * WINPTS * 8;          // 25.7 MB
    size_t need    = off_pay + sz_pay;

    if (ws_size >= need && nwin <= MAXWIN) {
        int* Pt = (int*)((char*)d_ws + off_pt);
        unsigned long long* payload = (unsigned long long*)((char*)d_ws + off_pay);

        bin_kernel<<<B * nwin, 256, 0, stream>>>(pts, bb, Pt, payload, N, nwin);
        trilerp_lds_kernel<<<B * NBIN, 128, 0, stream>>>(vel, Pt, payload, out, N, nwin);
    } else {
        int nchunk = (N + 255) / 256;
        long long blocks = (long long)B * nchunk * NSLAB;
        trilerp_pair_kernel<<<(int)blocks, 256, 0, stream>>>(vel, pts, bb, out, N, nchunk);
    }
}

// Round 16
// 184.204 us; speedup vs baseline: 1.0556x; 1.0556x over previous
//
#include <hip/hip_runtime.h>
#include <hip/hip_fp16.h>

// Trilinear grid interpolation — windowed binning + fp16-LDS-staged gather,
// 8-byte quantized payload, 8192-point windows (payload de-fragmentation).
//   velocity: [B, 3, G, G, G] f32, points: [B, N, 3] f32, bb: [3,2] f32
//   out: [B, N, 3] f32
//
// R14 lesson: smaller bins fragment payload runs below a 64B line -> line
// over-touch on both scatter and gather; per-block fixed overhead scales
// with block count. R15 = R13 structure (1024 bins, 1 block/bin, fp16 LDS
// 19.2KB, 8 blocks/CU) with WINPTS 4096->8192: runs avg ~8 pts (full lines),
// gather per-block overhead halves. 13-bit in-window idx fits 3x17+13 = 64b.

constexpr int G = 128;
constexpr long long G3 = (long long)G * G * G;   // 1<<21
constexpr int NSLAB = 8;            // == #XCDs
constexpr int NBU = 32, NBV = 32;   // 4x4-cell uv bins
constexpr int NBIN = NBU * NBV;     // 1024
constexpr int WINPTS = 8192;        // points per window block
constexpr int NIT = WINPTS / 256;   // 32
constexpr int MAXWIN = 64;          // gather LDS arrays cap (N <= 64*8192)

// ---------------- pass 1: windowed binning (hist + scan + scatter) ----------
__global__ __launch_bounds__(256) void bin_kernel(
    const float* __restrict__ pts,   // [B,N,3]
    const float* __restrict__ bb,    // [3,2]
    int* __restrict__ Pt,            // [B*NBIN][nwin] window-local bin offsets
    unsigned long long* __restrict__ payload,  // [B*nwin][WINPTS]
    int N, int nwin)
{
    __shared__ int hist[NBIN];
    __shared__ int psum[256];

    int b = blockIdx.x / nwin;
    int w = blockIdx.x % nwin;
    for (int i = threadIdx.x; i < NBIN; i += 256) hist[i] = 0;
    __syncthreads();

    const float Gm1 = (float)(G - 1);
    float bx0 = bb[0], bx1 = bb[1];
    float by0 = bb[2], by1 = bb[3];
    float bz0 = bb[4], bz1 = bb[5];
    long long pbase = (long long)b * N;
    int n0 = w * WINPTS;

    // phase 1: histogram (quantized bin; recomputed identically in phase 2)
    for (int it = 0; it < NIT; ++it) {
        int n = n0 + it * 256 + threadIdx.x;
        if (n < N) {
            const float* p = pts + (pbase + n) * 3;
            float u = (p[0] - bx0) / (bx1 - bx0) * Gm1;
            float v = (p[1] - by0) / (by1 - by0) * Gm1;
            u = fminf(fmaxf(u, 0.f), Gm1);
            v = fminf(fmaxf(v, 0.f), Gm1);
            unsigned int qu = (unsigned int)(u * 1024.0f);   // floor-quant
            unsigned int qv = (unsigned int)(v * 1024.0f);
            atomicAdd(&hist[((qu >> 12) << 5) | (qv >> 12)], 1);
        }
    }
    __syncthreads();

    // in-block exclusive scan of 1024 bins: thread t owns bins 4t..4t+3
    int t = threadIdx.x;
    int l0 = hist[4 * t], l1 = hist[4 * t + 1], l2 = hist[4 * t + 2], l3 = hist[4 * t + 3];
    int s = l0 + l1 + l2 + l3;
    psum[t] = s;
    __syncthreads();
    for (int off = 1; off < 256; off <<= 1) {
        int v = (t >= off) ? psum[t - off] : 0;
        __syncthreads();
        psum[t] += v;
        __syncthreads();
    }
    int run = psum[t] - s;   // exclusive prefix of this thread's 4 bins

    // write Pt (bin-major: [(b*NBIN+bin)*nwin + w]) and convert hist -> cursor
    long long prow = ((long long)b * NBIN + 4 * t) * nwin + w;
    Pt[prow]            = run; hist[4 * t]     = run; run += l0;
    Pt[prow + nwin]     = run; hist[4 * t + 1] = run; run += l1;
    Pt[prow + 2 * nwin] = run; hist[4 * t + 2] = run; run += l2;
    Pt[prow + 3 * nwin] = run; hist[4 * t + 3] = run; run += l3;
    __syncthreads();

    // phase 2: re-read (L2-hot), rank via LDS cursor, write 8B payload
    unsigned long long* seg = payload + (long long)(b * nwin + w) * WINPTS;
    for (int it = 0; it < NIT; ++it) {
        int n = n0 + it * 256 + threadIdx.x;
        if (n < N) {
            const float* p = pts + (pbase + n) * 3;
            float u  = (p[0] - bx0) / (bx1 - bx0) * Gm1;
            float v  = (p[1] - by0) / (by1 - by0) * Gm1;
            float wz = (p[2] - bz0) / (bz1 - bz0) * Gm1;
            u  = fminf(fmaxf(u, 0.f), Gm1);
            v  = fminf(fmaxf(v, 0.f), Gm1);
            wz = fminf(fmaxf(wz, 0.f), Gm1);
            unsigned int qu = (unsigned int)(u * 1024.0f);
            unsigned int qv = (unsigned int)(v * 1024.0f);
            unsigned int qw = (unsigned int)(wz * 1024.0f);
            int nl = n - n0;                                  // 13 bits
            unsigned long long q = (unsigned long long)qu
                                 | ((unsigned long long)qv << 17)
                                 | ((unsigned long long)qw << 34)
                                 | ((unsigned long long)nl << 51);
            int bin = ((qu >> 12) << 5) | (qv >> 12);
            int pos = atomicAdd(&hist[bin], 1);
            seg[pos] = q;
        }
    }
}

// ---------------- pass 2: binned gather, fp16 planar LDS staging ------------
__global__ __launch_bounds__(256) void trilerp_lds_kernel(
    const float* __restrict__ vel,       // [B,3,G,G,G]
    const int* __restrict__ Pt,          // [B*NBIN][nwin]
    const unsigned long long* __restrict__ payload,  // [B*nwin][WINPTS]
    float* __restrict__ out,             // [B,N,3]
    int N, int nwin)
{
    // blockIdx.x = slab + 8*(b*128 + j*32 + iv4); iu4 = slab*4 + j
    __shared__ unsigned short s_h[3 * 25 * 128];  // 19.2 KB -> 8 blocks/CU
    __shared__ int loc[MAXWIN];
    __shared__ int sc[MAXWIN];                    // counts -> inclusive prefix

    int x = blockIdx.x;
    int slab = x & (NSLAB - 1);
    int rest = x >> 3;
    int b    = rest >> 7;
    int r2   = rest & 127;
    int iu4  = (slab << 2) | (r2 >> 5);
    int iv4  = r2 & 31;
    int binLocal = (iu4 << 5) | iv4;
    long long lin = (long long)b * NBIN + binLocal;

    int tid = threadIdx.x;
    if (tid < nwin) {
        int l  = Pt[lin * nwin + tid];
        int nl = (binLocal < NBIN - 1) ? Pt[(lin + 1) * nwin + tid]
                                       : min(WINPTS, N - tid * WINPTS);
        loc[tid] = l;
        sc[tid]  = nl - l;                  // count of this bin in window tid
    } else if (tid < MAXWIN) {
        loc[tid] = 0; sc[tid] = 0;
    }

    // stage 3 channels x 25 rows x 128 cells: f32 global -> fp16 LDS, coalesced
    int u0 = iu4 << 2, v0 = iv4 << 2;
    for (int k = 0; k < 10; ++k) {
        int idx = tid + k * 256;
        if (idx < 2400) {
            int f4 = idx & 31;
            int ru = idx >> 5;
            int ch = ru / 25;
            int r  = ru - ch * 25;
            int gu = min(u0 + r / 5, G - 1);
            int gv = min(v0 + (r - (r / 5) * 5), G - 1);
            long long src = (((long long)b * 3 + ch) << 21) + ((long long)gu << 14) + (gv << 7) + (f4 << 2);
            float4 val = *reinterpret_cast<const float4*>(vel + src);
            unsigned int lo32 = (unsigned int)__half_as_ushort(__float2half(val.x))
                              | ((unsigned int)__half_as_ushort(__float2half(val.y)) << 16);
            unsigned int hi32 = (unsigned int)__half_as_ushort(__float2half(val.z))
                              | ((unsigned int)__half_as_ushort(__float2half(val.w)) << 16);
            *reinterpret_cast<uint2*>(&s_h[((ch * 25 + r) << 7) + (f4 << 2)]) = make_uint2(lo32, hi32);
        }
    }
    __syncthreads();

    // inclusive prefix over window counts (all threads hit barriers)
    for (int off = 1; off < MAXWIN; off <<= 1) {
        int v = 0;
        if (tid < MAXWIN && tid >= off) v = sc[tid - off];
        __syncthreads();
        if (tid < MAXWIN) sc[tid] += v;
        __syncthreads();
    }
    int total = sc[nwin - 1];
    const float INV1024 = 1.0f / 1024.0f;

    auto h2f = [](unsigned short us) -> float {
        return __half2float(__ushort_as_half(us));
    };

    for (int i = tid; i < total; i += 256) {
        // smallest w with sc[w] > i
        int lo2 = 0, hi2 = nwin - 1;
        while (lo2 < hi2) { int mid = (lo2 + hi2) >> 1; if (sc[mid] > i) hi2 = mid; else lo2 = mid + 1; }
        int w = lo2;
        int excl = (w == 0) ? 0 : sc[w - 1];
        long long pidx = (long long)(b * nwin + w) * WINPTS + loc[w] + (i - excl);
        unsigned long long q = payload[pidx];
        unsigned int qu = (unsigned int)(q & 0x1FFFF);
        unsigned int qv = (unsigned int)((q >> 17) & 0x1FFFF);
        unsigned int qw = (unsigned int)((q >> 34) & 0x1FFFF);
        int nl = (int)(q >> 51);
        int t = (int)((long long)b * N + w * WINPTS + nl);

        float u  = (float)qu * INV1024;
        float v  = (float)qv * INV1024;
        float wq = (float)qw * INV1024;

        float fu = floorf(u);     // quantized values already in [0, 127]
        float fv = floorf(v);
        float fw = floorf(wq);

        float du = u - fu, dv = v - fv, dw = wq - fw;  // frac
        float gu = fu + 1.0f - u;                      // gfrac
        float gv = fv + 1.0f - v;
        float gw = fw + 1.0f - wq;

        int iu1 = (int)fu, iv1 = (int)fv, iw1 = (int)fw;
        int iu2 = min(iu1 + 1, G - 1);
        int iv2 = min(iv1 + 1, G - 1);
        int iwb = min(iw1, G - 2);
        bool lo = (iw1 <= G - 2);

        float w11 = gu * gv, w12 = gu * dv, w21 = du * gv, w22 = du * dv;

        int du1 = iu1 - u0, dv1 = iv1 - v0;
        int du2 = iu2 - u0, dv2 = iv2 - v0;

        float o[3];
        #pragma unroll
        for (int ch = 0; ch < 3; ++ch) {
            int rb = ch * 25;
            int b11 = (rb + du1 * 5 + dv1) << 7;
            int b12 = (rb + du1 * 5 + dv2) << 7;
            int b21 = (rb + du2 * 5 + dv1) << 7;
            int b22 = (rb + du2 * 5 + dv2) << 7;
            float l11 = h2f(s_h[b11 + iwb]), h11 = h2f(s_h[b11 + iwb + 1]);
            float l12 = h2f(s_h[b12 + iwb]), h12 = h2f(s_h[b12 + iwb + 1]);
            float l21 = h2f(s_h[b21 + iwb]), h21 = h2f(s_h[b21 + iwb + 1]);
            float l22 = h2f(s_h[b22 + iwb]), h22 = h2f(s_h[b22 + iwb + 1]);
            float a11 = lo ? l11 : h11;
            float a12 = lo ? l12 : h12;
            float a21 = lo ? l21 : h21;
            float a22 = lo ? l22 : h22;
            o[ch] = w11 * (gw * a11 + dw * h11)
                  + w12 * (gw * a12 + dw * h12)
                  + w21 * (gw * a21 + dw * h21)
                  + w22 * (gw * a22 + dw * h22);
        }

        float* op = out + (long long)t * 3;
        op[0] = o[0]; op[1] = o[1]; op[2] = o[2];
    }
}

// ---- fallback (R3): f32 broadcast scan, no workspace ----
__global__ __launch_bounds__(256) void trilerp_pair_kernel(
    const float* __restrict__ vel, const float* __restrict__ pts,
    const float* __restrict__ bb, float* __restrict__ out,
    int N, int nchunk)
{
    int bid  = blockIdx.x;
    int slab = bid & (NSLAB - 1);
    int t    = bid >> 3;
    int c    = t % nchunk;
    int b    = t / nchunk;
    int n = c * 256 + threadIdx.x;
    if (n >= N) return;

    float bx0 = bb[0], bx1 = bb[1];
    float by0 = bb[2], by1 = bb[3];
    float bz0 = bb[4], bz1 = bb[5];
    long long pi = (long long)b * N + n;
    const float* p = pts + pi * 3;
    float px = p[0], py = p[1], pz = p[2];
    const float Gm1 = (float)(G - 1);
    float u = (px - bx0) / (bx1 - bx0) * Gm1;
    float fu = fminf(fmaxf(floorf(u), 0.f), Gm1);
    int iu1 = (int)fu;
    if ((iu1 >> 4) != slab) return;
    float v = (py - by0) / (by1 - by0) * Gm1;
    float w = (pz - bz0) / (bz1 - bz0) * Gm1;
    float fv = fminf(fmaxf(floorf(v), 0.f), Gm1);
    float fw = fminf(fmaxf(floorf(w), 0.f), Gm1);
    float du = u - fu, dv = v - fv, dw = w - fw;
    float gu = fu + 1.0f - u, gv = fv + 1.0f - v, gw = fw + 1.0f - w;
    int iv1 = (int)fv, iw1 = (int)fw;
    int iu2 = min(iu1 + 1, G - 1);
    int iv2 = min(iv1 + 1, G - 1);
    int iwb = min(iw1, G - 2);
    bool lo = (iw1 <= G - 2);
    float w11 = gu * gv, w12 = gu * dv, w21 = du * gv, w22 = du * dv;
    const float* vb = vel + (long long)b * 3 * G3;
    long long o11 = (long long)((iu1 << 7) + iv1) * G + iwb;
    long long o12 = (long long)((iu1 << 7) + iv2) * G + iwb;
    long long o21 = (long long)((iu2 << 7) + iv1) * G + iwb;
    long long o22 = (long long)((iu2 << 7) + iv2) * G + iwb;
    float o[3];
    #pragma unroll
    for (int chn = 0; chn < 3; ++chn) {
        const float* vc = vb + (long long)chn * G3;
        float2 p11 = *reinterpret_cast<const float2*>(vc + o11);
        float2 p12 = *reinterpret_cast<const float2*>(vc + o12);
        float2 p21 = *reinterpret_cast<const float2*>(vc + o21);
        float2 p22 = *reinterpret_cast<const float2*>(vc + o22);
        float a11 = lo ? p11.x : p11.y;
        float a12 = lo ? p12.x : p12.y;
        float a21 = lo ? p21.x : p21.y;
        float a22 = lo ? p22.x : p22.y;
        o[chn] = w11 * (gw * a11 + dw * p11.y)
               + w12 * (gw * a12 + dw * p12.y)
               + w21 * (gw * a21 + dw * p21.y)
               + w22 * (gw * a22 + dw * p22.y);
    }
    float* op = out + pi * 3;
    op[0] = o[0]; op[1] = o[1]; op[2] = o[2];
}

extern "C" void kernel_launch(void* const* d_in, const int* in_sizes, int n_in,
                              void* d_out, int out_size, void* d_ws, size_t ws_size,
                              hipStream_t stream) {
    const float* vel = (const float*)d_in[0];
    const float* pts = (const float*)d_in[1];
    const float* bb  = (const float*)d_in[2];
    float* out = (float*)d_out;

    int B = (int)(in_sizes[0] / (3 * G3));       // 16
    int N = in_sizes[1] / (3 * B);               // 200000
    int nwin = (N + WINPTS - 1) / WINPTS;        // 25

    auto align256 = [](size_t x) { return (x + 255) & ~(size_t)255; };
    size_t off_pt  = 0;
    size_t sz_pt   = (size_t)B * NBIN * nwin * 4;            // 1.64 MB
    size_t off_pay = align256(off_pt + sz_pt);
    size_t sz_pay  = (size_t)B * nwin * WINPTS * 8;          // 26.2 MB
    size_t need    = off_pay + sz_pay;

    if (ws_size >= need && nwin <= MAXWIN) {
        int* Pt = (int*)((char*)d_ws + off_pt);
        unsigned long long* payload = (unsigned long long*)((char*)d_ws + off_pay);

        bin_kernel<<<B * nwin, 256, 0, stream>>>(pts, bb, Pt, payload, N, nwin);
        trilerp_lds_kernel<<<B * NBIN, 256, 0, stream>>>(vel, Pt, payload, out, N, nwin);
    } else {
        int nchunk = (N + 255) / 256;
        long long blocks = (long long)B * nchunk * NSLAB;
        trilerp_pair_kernel<<<(int)blocks, 256, 0, stream>>>(vel, pts, bb, out, N, nchunk);
    }
}

// Round 17
// 165.690 us; speedup vs baseline: 1.1736x; 1.1117x over previous
//
#include <hip/hip_runtime.h>
#include <hip/hip_fp16.h>

// Trilinear grid interpolation — windowed binning + fp16-LDS-staged gather,
// 8-byte quantized payload. (R13 configuration — best measured: 166 us.)
//   velocity: [B, 3, G, G, G] f32, points: [B, N, 3] f32, bb: [3,2] f32
//   out: [B, N, 3] f32
//
// Structure settled by R1-R15 evidence:
//  - gathers must be served from LDS (global gathers are L1-miss bound: R1-R4)
//  - stage f32->fp16 during LDS write; 19.2KB tile -> 8 blocks/CU (R11)
//  - never duplicate stage bytes (R12 pair-split regressed)
//  - 8B quantized payload (R13: -30us; bytes are the currency)
//  - 1024 bins / WINPTS=4096 optimal (R14 smaller bins, R15 bigger windows
//    both regressed: fragmentation & per-block overhead vs reg-cache loss)

constexpr int G = 128;
constexpr long long G3 = (long long)G * G * G;   // 1<<21
constexpr int NSLAB = 8;            // == #XCDs
constexpr int NBU = 32, NBV = 32;   // 4x4-cell uv bins
constexpr int NBIN = NBU * NBV;     // 1024
constexpr int WINPTS = 4096;        // points per window block
constexpr int NIT = WINPTS / 256;   // 16
constexpr int MAXWIN = 64;          // gather LDS arrays cap (N <= 64*4096)

// ---------------- pass 1: windowed binning (hist + scan + scatter) ----------
__global__ __launch_bounds__(256) void bin_kernel(
    const float* __restrict__ pts,   // [B,N,3]
    const float* __restrict__ bb,    // [3,2]
    int* __restrict__ Pt,            // [B*NBIN][nwin] window-local bin offsets
    unsigned long long* __restrict__ payload,  // [B*nwin][WINPTS]
    int N, int nwin)
{
    __shared__ int hist[NBIN];
    __shared__ int psum[256];

    int b = blockIdx.x / nwin;
    int w = blockIdx.x % nwin;
    for (int i = threadIdx.x; i < NBIN; i += 256) hist[i] = 0;
    __syncthreads();

    const float Gm1 = (float)(G - 1);
    float bx0 = bb[0], bx1 = bb[1];
    float by0 = bb[2], by1 = bb[3];
    float bz0 = bb[4], bz1 = bb[5];
    long long pbase = (long long)b * N;
    int n0 = w * WINPTS;

    // phase 1: histogram; quantize+cache q in registers (static idx via unroll)
    unsigned long long qc[NIT];
    #pragma unroll
    for (int it = 0; it < NIT; ++it) {
        int n = n0 + it * 256 + threadIdx.x;
        qc[it] = ~0ull;
        if (n < N) {
            const float* p = pts + (pbase + n) * 3;
            float u  = (p[0] - bx0) / (bx1 - bx0) * Gm1;
            float v  = (p[1] - by0) / (by1 - by0) * Gm1;
            float wz = (p[2] - bz0) / (bz1 - bz0) * Gm1;
            u  = fminf(fmaxf(u, 0.f), Gm1);
            v  = fminf(fmaxf(v, 0.f), Gm1);
            wz = fminf(fmaxf(wz, 0.f), Gm1);
            unsigned int qu = (unsigned int)(u * 1024.0f);   // floor-quant
            unsigned int qv = (unsigned int)(v * 1024.0f);
            unsigned int qw = (unsigned int)(wz * 1024.0f);
            int nl = n - n0;                                  // 12 bits
            qc[it] = (unsigned long long)qu
                   | ((unsigned long long)qv << 17)
                   | ((unsigned long long)qw << 34)
                   | ((unsigned long long)nl << 51);
            atomicAdd(&hist[((qu >> 12) << 5) | (qv >> 12)], 1);
        }
    }
    __syncthreads();

    // in-block exclusive scan of 1024 bins: thread t owns bins 4t..4t+3
    int t = threadIdx.x;
    int l0 = hist[4 * t], l1 = hist[4 * t + 1], l2 = hist[4 * t + 2], l3 = hist[4 * t + 3];
    int s = l0 + l1 + l2 + l3;
    psum[t] = s;
    __syncthreads();
    for (int off = 1; off < 256; off <<= 1) {
        int v = (t >= off) ? psum[t - off] : 0;
        __syncthreads();
        psum[t] += v;
        __syncthreads();
    }
    int run = psum[t] - s;   // exclusive prefix of this thread's 4 bins

    // write Pt (bin-major: [(b*NBIN+bin)*nwin + w]) and convert hist -> cursor
    long long prow = ((long long)b * NBIN + 4 * t) * nwin + w;
    Pt[prow]            = run; hist[4 * t]     = run; run += l0;
    Pt[prow + nwin]     = run; hist[4 * t + 1] = run; run += l1;
    Pt[prow + 2 * nwin] = run; hist[4 * t + 2] = run; run += l2;
    Pt[prow + 3 * nwin] = run; hist[4 * t + 3] = run; run += l3;
    __syncthreads();

    // phase 2: rank via LDS cursor, write 8B payload into private segment
    unsigned long long* seg = payload + (long long)(b * nwin + w) * WINPTS;
    #pragma unroll
    for (int it = 0; it < NIT; ++it) {
        unsigned long long q = qc[it];
        if (q != ~0ull) {
            unsigned int qu = (unsigned int)(q & 0x1FFFF);
            unsigned int qv = (unsigned int)((q >> 17) & 0x1FFFF);
            int bin = ((qu >> 12) << 5) | (qv >> 12);
            int pos = atomicAdd(&hist[bin], 1);
            seg[pos] = q;
        }
    }
}

// ---------------- pass 2: binned gather, fp16 planar LDS staging ------------
__global__ __launch_bounds__(256) void trilerp_lds_kernel(
    const float* __restrict__ vel,       // [B,3,G,G,G]
    const int* __restrict__ Pt,          // [B*NBIN][nwin]
    const unsigned long long* __restrict__ payload,  // [B*nwin][WINPTS]
    float* __restrict__ out,             // [B,N,3]
    int N, int nwin)
{
    // blockIdx.x = slab + 8*(b*128 + j*32 + iv4); iu4 = slab*4 + j
    __shared__ unsigned short s_h[3 * 25 * 128];  // 19.2 KB -> 8 blocks/CU
    __shared__ int loc[MAXWIN];
    __shared__ int sc[MAXWIN];                    // counts -> inclusive prefix

    int x = blockIdx.x;
    int slab = x & (NSLAB - 1);
    int rest = x >> 3;
    int b    = rest >> 7;
    int r2   = rest & 127;
    int iu4  = (slab << 2) | (r2 >> 5);
    int iv4  = r2 & 31;
    int binLocal = (iu4 << 5) | iv4;
    long long lin = (long long)b * NBIN + binLocal;

    int tid = threadIdx.x;
    if (tid < nwin) {
        int l  = Pt[lin * nwin + tid];
        int nl = (binLocal < NBIN - 1) ? Pt[(lin + 1) * nwin + tid]
                                       : min(WINPTS, N - tid * WINPTS);
        loc[tid] = l;
        sc[tid]  = nl - l;                  // count of this bin in window tid
    } else if (tid < MAXWIN) {
        loc[tid] = 0; sc[tid] = 0;
    }

    // stage 3 channels x 25 rows x 128 cells: f32 global -> fp16 LDS, coalesced
    int u0 = iu4 << 2, v0 = iv4 << 2;
    for (int k = 0; k < 10; ++k) {
        int idx = tid + k * 256;
        if (idx < 2400) {
            int f4 = idx & 31;
            int ru = idx >> 5;
            int ch = ru / 25;
            int r  = ru - ch * 25;
            int gu = min(u0 + r / 5, G - 1);
            int gv = min(v0 + (r - (r / 5) * 5), G - 1);
            long long src = (((long long)b * 3 + ch) << 21) + ((long long)gu << 14) + (gv << 7) + (f4 << 2);
            float4 val = *reinterpret_cast<const float4*>(vel + src);
            unsigned int lo32 = (unsigned int)__half_as_ushort(__float2half(val.x))
                              | ((unsigned int)__half_as_ushort(__float2half(val.y)) << 16);
            unsigned int hi32 = (unsigned int)__half_as_ushort(__float2half(val.z))
                              | ((unsigned int)__half_as_ushort(__float2half(val.w)) << 16);
            *reinterpret_cast<uint2*>(&s_h[((ch * 25 + r) << 7) + (f4 << 2)]) = make_uint2(lo32, hi32);
        }
    }
    __syncthreads();

    // inclusive prefix over window counts (all threads hit barriers)
    for (int off = 1; off < MAXWIN; off <<= 1) {
        int v = 0;
        if (tid < MAXWIN && tid >= off) v = sc[tid - off];
        __syncthreads();
        if (tid < MAXWIN) sc[tid] += v;
        __syncthreads();
    }
    int total = sc[nwin - 1];
    const float INV1024 = 1.0f / 1024.0f;

    auto h2f = [](unsigned short us) -> float {
        return __half2float(__ushort_as_half(us));
    };

    for (int i = tid; i < total; i += 256) {
        // smallest w with sc[w] > i
        int lo2 = 0, hi2 = nwin - 1;
        while (lo2 < hi2) { int mid = (lo2 + hi2) >> 1; if (sc[mid] > i) hi2 = mid; else lo2 = mid + 1; }
        int w = lo2;
        int excl = (w == 0) ? 0 : sc[w - 1];
        long long pidx = (long long)(b * nwin + w) * WINPTS + loc[w] + (i - excl);
        unsigned long long q = payload[pidx];
        unsigned int qu = (unsigned int)(q & 0x1FFFF);
        unsigned int qv = (unsigned int)((q >> 17) & 0x1FFFF);
        unsigned int qw = (unsigned int)((q >> 34) & 0x1FFFF);
        int nl = (int)(q >> 51);
        int t = (int)((long long)b * N + w * WINPTS + nl);

        float u  = (float)qu * INV1024;
        float v  = (float)qv * INV1024;
        float wq = (float)qw * INV1024;

        float fu = floorf(u);     // quantized values already in [0, 127]
        float fv = floorf(v);
        float fw = floorf(wq);

        float du = u - fu, dv = v - fv, dw = wq - fw;  // frac
        float gu = fu + 1.0f - u;                      // gfrac
        float gv = fv + 1.0f - v;
        float gw = fw + 1.0f - wq;

        int iu1 = (int)fu, iv1 = (int)fv, iw1 = (int)fw;
        int iu2 = min(iu1 + 1, G - 1);
        int iv2 = min(iv1 + 1, G - 1);
        int iwb = min(iw1, G - 2);
        bool lo = (iw1 <= G - 2);

        float w11 = gu * gv, w12 = gu * dv, w21 = du * gv, w22 = du * dv;

        int du1 = iu1 - u0, dv1 = iv1 - v0;
        int du2 = iu2 - u0, dv2 = iv2 - v0;

        float o[3];
        #pragma unroll
        for (int ch = 0; ch < 3; ++ch) {
            int rb = ch * 25;
            int b11 = (rb + du1 * 5 + dv1) << 7;
            int b12 = (rb + du1 * 5 + dv2) << 7;
            int b21 = (rb + du2 * 5 + dv1) << 7;
            int b22 = (rb + du2 * 5 + dv2) << 7;
            float l11 = h2f(s_h[b11 + iwb]), h11 = h2f(s_h[b11 + iwb + 1]);
            float l12 = h2f(s_h[b12 + iwb]), h12 = h2f(s_h[b12 + iwb + 1]);
            float l21 = h2f(s_h[b21 + iwb]), h21 = h2f(s_h[b21 + iwb + 1]);
            float l22 = h2f(s_h[b22 + iwb]), h22 = h2f(s_h[b22 + iwb + 1]);
            float a11 = lo ? l11 : h11;
            float a12 = lo ? l12 : h12;
            float a21 = lo ? l21 : h21;
            float a22 = lo ? l22 : h22;
            o[ch] = w11 * (gw * a11 + dw * h11)
                  + w12 * (gw * a12 + dw * h12)
                  + w21 * (gw * a21 + dw * h21)
                  + w22 * (gw * a22 + dw * h22);
        }

        float* op = out + (long long)t * 3;
        op[0] = o[0]; op[1] = o[1]; op[2] = o[2];
    }
}

// ---- fallback (R3): f32 broadcast scan, no workspace ----
__global__ __launch_bounds__(256) void trilerp_pair_kernel(
    const float* __restrict__ vel, const float* __restrict__ pts,
    const float* __restrict__ bb, float* __restrict__ out,
    int N, int nchunk)
{
    int bid  = blockIdx.x;
    int slab = bid & (NSLAB - 1);
    int t    = bid >> 3;
    int c    = t % nchunk;
    int b    = t / nchunk;
    int n = c * 256 + threadIdx.x;
    if (n >= N) return;

    float bx0 = bb[0], bx1 = bb[1];
    float by0 = bb[2], by1 = bb[3];
    float bz0 = bb[4], bz1 = bb[5];
    long long pi = (long long)b * N + n;
    const float* p = pts + pi * 3;
    float px = p[0], py = p[1], pz = p[2];
    const float Gm1 = (float)(G - 1);
    float u = (px - bx0) / (bx1 - bx0) * Gm1;
    float fu = fminf(fmaxf(floorf(u), 0.f), Gm1);
    int iu1 = (int)fu;
    if ((iu1 >> 4) != slab) return;
    float v = (py - by0) / (by1 - by0) * Gm1;
    float w = (pz - bz0) / (bz1 - bz0) * Gm1;
    float fv = fminf(fmaxf(floorf(v), 0.f), Gm1);
    float fw = fminf(fmaxf(floorf(w), 0.f), Gm1);
    float du = u - fu, dv = v - fv, dw = w - fw;
    float gu = fu + 1.0f - u, gv = fv + 1.0f - v, gw = fw + 1.0f - w;
    int iv1 = (int)fv, iw1 = (int)fw;
    int iu2 = min(iu1 + 1, G - 1);
    int iv2 = min(iv1 + 1, G - 1);
    int iwb = min(iw1, G - 2);
    bool lo = (iw1 <= G - 2);
    float w11 = gu * gv, w12 = gu * dv, w21 = du * gv, w22 = du * dv;
    const float* vb = vel + (long long)b * 3 * G3;
    long long o11 = (long long)((iu1 << 7) + iv1) * G + iwb;
    long long o12 = (long long)((iu1 << 7) + iv2) * G + iwb;
    long long o21 = (long long)((iu2 << 7) + iv1) * G + iwb;
    long long o22 = (long long)((iu2 << 7) + iv2) * G + iwb;
    float o[3];
    #pragma unroll
    for (int chn = 0; chn < 3; ++chn) {
        const float* vc = vb + (long long)chn * G3;
        float2 p11 = *reinterpret_cast<const float2*>(vc + o11);
        float2 p12 = *reinterpret_cast<const float2*>(vc + o12);
        float2 p21 = *reinterpret_cast<const float2*>(vc + o21);
        float2 p22 = *reinterpret_cast<const float2*>(vc + o22);
        float a11 = lo ? p11.x : p11.y;
        float a12 = lo ? p12.x : p12.y;
        float a21 = lo ? p21.x : p21.y;
        float a22 = lo ? p22.x : p22.y;
        o[chn] = w11 * (gw * a11 + dw * p11.y)
               + w12 * (gw * a12 + dw * p12.y)
               + w21 * (gw * a21 + dw * p21.y)
               + w22 * (gw * a22 + dw * p22.y);
    }
    float* op = out + pi * 3;
    op[0] = o[0]; op[1] = o[1]; op[2] = o[2];
}

extern "C" void kernel_launch(void* const* d_in, const int* in_sizes, int n_in,
                              void* d_out, int out_size, void* d_ws, size_t ws_size,
                              hipStream_t stream) {
    const float* vel = (const float*)d_in[0];
    const float* pts = (const float*)d_in[1];
    const float* bb  = (const float*)d_in[2];
    float* out = (float*)d_out;

    int B = (int)(in_sizes[0] / (3 * G3));       // 16
    int N = in_sizes[1] / (3 * B);               // 200000
    int nwin = (N + WINPTS - 1) / WINPTS;        // 49

    auto align256 = [](size_t x) { return (x + 255) & ~(size_t)255; };
    size_t off_pt  = 0;
    size_t sz_pt   = (size_t)B * NBIN * nwin * 4;            // 3.2 MB
    size_t off_pay = align256(off_pt + sz_pt);
    size_t sz_pay  = (size_t)B * nwin * WINPTS * 8;          // 25.7 MB
    size_t need    = off_pay + sz_pay;

    if (ws_size >= need && nwin <= MAXWIN) {
        int* Pt = (int*)((char*)d_ws + off_pt);
        unsigned long long* payload = (unsigned long long*)((char*)d_ws + off_pay);

        bin_kernel<<<B * nwin, 256, 0, stream>>>(pts, bb, Pt, payload, N, nwin);
        trilerp_lds_kernel<<<B * NBIN, 256, 0, stream>>>(vel, Pt, payload, out, N, nwin);
    } else {
        int nchunk = (N + 255) / 256;
        long long blocks = (long long)B * nchunk * NSLAB;
        trilerp_pair_kernel<<<(int)blocks, 256, 0, stream>>>(vel, pts, bb, out, N, nchunk);
    }
}